// Round 11
// baseline (387.368 us; speedup 1.0000x reference)
//
#include <hip/hip_runtime.h>
#include <hip/hip_bf16.h>

// Problem constants (fixed by reference): N=262144 rows, D=64, K=512 codes.
#define N_ROWS 262144
#define DIM 64
#define KC 512
#define BLK 512                        // threads/block; 8 waves = 2/SIMD, 1 block/CU
#define RPT 2                          // rows per thread
#define LDS_FLOATS (KC * DIM + KC)     // codebook + esq = 33280 floats = 133120 B

// d_out layout — FLOAT32 (verified passing):
//   out[0]                      = loss
//   out[1 .. 1+N*D)             = quantized [N,64] row-major
//   out[1+N*D .. 1+N*D+N)       = float(encoding_indices)
//
// Numerics replicated exactly (indices must match np.argmin of f32 dists):
//   x_sq, e_sq : numpy pairwise sum, n=64 => 8-accumulator striped scheme
//   dot        : sequential fused-FMA chain, ascending j (OpenBLAS kernel)
//   d          : fl( fl(x_sq + e_sq_k) - 2*dot_k ), contraction off
//   argmin     : strict <, first-min-wins (k ascending)
//
// Pipe model (R7/R8/R10 evidence): uniform-broadcast ds_read_b128 ~ 6 cyc
// of LDS-pipe time. R7 (RPT=1): LDS demand 327us => observed 330 (LDS-bound,
// VALU hidden by 4-wave TLP). R8 (RPT=2): LDS 164 + VALU 115 SERIALIZED =>
// observed 276 (2 waves/SIMD can't overlap own loads with own FMA bursts).
// R10 (source sw-pipeline): compiler rescheduled it away — neutral.
// R11: split e-traffic across pipes. Code k from LDS (DS pipe), code k+1
// from GLOBAL codebook (TA/VMEM pipe; 128KB is L1/L2-resident; wave-uniform
// 16B load = one cache access broadcast). LDS demand halves to 82us; VMEM
// carries 82us on separate hardware; both fit under the 512-cyc FMA burst.
// Structural — the compiler can't re-serialize it onto one pipe. Values
// are bit-identical to the staged copies; numerics untouched.

// numpy pairwise sum of squares for n=64 (scalar path, PW_BLOCKSIZE=128).
__device__ __forceinline__ float np_sumsq64(const float* a) {
#pragma clang fp contract(off)
    float r[8];
#pragma unroll
    for (int j = 0; j < 8; ++j) r[j] = a[j] * a[j];
#pragma unroll
    for (int i = 8; i < 64; i += 8)
#pragma unroll
        for (int j = 0; j < 8; ++j) r[j] = r[j] + a[i + j] * a[i + j];
    return ((r[0] + r[1]) + (r[2] + r[3])) + ((r[4] + r[5]) + (r[6] + r[7]));
}

// ---- kernel 1: e_sq_k with numpy bit-exact summation ----
__global__ void esq_kernel(const float* __restrict__ cb, float* __restrict__ esq) {
    int k = blockIdx.x * blockDim.x + threadIdx.x;
    if (k < KC) esq[k] = np_sumsq64(cb + k * DIM);
}

// ---- kernel 2: main VQ — TWO rows per thread; e from LDS + global (split) ----
__global__ __launch_bounds__(BLK)
__attribute__((amdgpu_waves_per_eu(2, 2)))   // grid-exact occupancy; 256-VGPR budget
void vq_kernel(
    const float* __restrict__ x, const float* __restrict__ cb,
    const float* __restrict__ esq_g, float* __restrict__ out,
    float* __restrict__ loss_acc)
{
    extern __shared__ float smem[];
    float* cbs  = smem;             // [512*64] codebook, k-major (global layout)
    float* esql = smem + KC * DIM;  // [512]

    const int tid  = threadIdx.x;
    const int lane = tid & 63;
    const int row0 = blockIdx.x * (BLK * RPT) + tid;   // rows row0 and row0+BLK
    const int row1 = row0 + BLK;

    // ---- cooperative stage: 128KB codebook + 2KB esq, fully coalesced ----
    {
        const float4* g4 = reinterpret_cast<const float4*>(cb);
        float4*       s4 = reinterpret_cast<float4*>(cbs);
#pragma unroll
        for (int i = 0; i < (KC * DIM / 4) / BLK; ++i)   // 16 iters
            s4[tid + i * BLK] = g4[tid + i * BLK];
        if (tid < KC) esql[tid] = esq_g[tid];
    }

    // Two rows into 128 VGPRs — overlaps staging latency.
    float xr0[DIM], xr1[DIM];
    {
        const float4* xv0 = reinterpret_cast<const float4*>(x + (size_t)row0 * DIM);
        const float4* xv1 = reinterpret_cast<const float4*>(x + (size_t)row1 * DIM);
#pragma unroll
        for (int j = 0; j < DIM / 4; ++j) {
            float4 v0 = xv0[j], v1 = xv1[j];
            xr0[4 * j + 0] = v0.x; xr0[4 * j + 1] = v0.y;
            xr0[4 * j + 2] = v0.z; xr0[4 * j + 3] = v0.w;
            xr1[4 * j + 0] = v1.x; xr1[4 * j + 1] = v1.y;
            xr1[4 * j + 2] = v1.z; xr1[4 * j + 3] = v1.w;
        }
    }

    // numpy-exact ||x||^2 per row.
    const float xsq0 = np_sumsq64(xr0);
    const float xsq1 = np_sumsq64(xr1);

    __syncthreads();   // staging complete

    // 2 codes x 2 rows per iter = 4 independent sequential fused-FMA chains.
    // Code k streams from LDS (DS pipe); code k+1 streams from global
    // (VMEM pipe, L1/L2-hot, wave-uniform broadcast). Same bits either way.
    float best0 = 3.4e38f, best1 = 3.4e38f;
    int bidx0 = 0, bidx1 = 0;
#pragma unroll 1
    for (int k = 0; k < KC; k += 2) {
        const float4* ea = reinterpret_cast<const float4*>(cbs + k * DIM);          // LDS
        const float4* eb = reinterpret_cast<const float4*>(cb + (size_t)(k + 1) * DIM); // global
        float dot00 = 0.f, dot01 = 0.f, dot10 = 0.f, dot11 = 0.f;
#pragma unroll
        for (int c = 0; c < DIM / 4; ++c) {
            const float4 a = ea[c];
            const float4 b = eb[c];
            dot00 = fmaf(xr0[4 * c + 0], a.x, dot00);
            dot01 = fmaf(xr0[4 * c + 0], b.x, dot01);
            dot10 = fmaf(xr1[4 * c + 0], a.x, dot10);
            dot11 = fmaf(xr1[4 * c + 0], b.x, dot11);
            dot00 = fmaf(xr0[4 * c + 1], a.y, dot00);
            dot01 = fmaf(xr0[4 * c + 1], b.y, dot01);
            dot10 = fmaf(xr1[4 * c + 1], a.y, dot10);
            dot11 = fmaf(xr1[4 * c + 1], b.y, dot11);
            dot00 = fmaf(xr0[4 * c + 2], a.z, dot00);
            dot01 = fmaf(xr0[4 * c + 2], b.z, dot01);
            dot10 = fmaf(xr1[4 * c + 2], a.z, dot10);
            dot11 = fmaf(xr1[4 * c + 2], b.z, dot11);
            dot00 = fmaf(xr0[4 * c + 3], a.w, dot00);
            dot01 = fmaf(xr0[4 * c + 3], b.w, dot01);
            dot10 = fmaf(xr1[4 * c + 3], a.w, dot10);
            dot11 = fmaf(xr1[4 * c + 3], b.w, dot11);
        }
        float d00, d01, d10, d11;
        {
#pragma clang fp contract(off)
            const float e0 = esql[k + 0], e1 = esql[k + 1];
            d00 = (xsq0 + e0) - 2.0f * dot00;  // 2*dot exact; each op rounds
            d01 = (xsq0 + e1) - 2.0f * dot01;
            d10 = (xsq1 + e0) - 2.0f * dot10;
            d11 = (xsq1 + e1) - 2.0f * dot11;
        }
        // strict <, ascending k: first-min-wins preserved (per row).
        if (d00 < best0) { best0 = d00; bidx0 = k + 0; }
        if (d01 < best0) { best0 = d01; bidx0 = k + 1; }
        if (d10 < best1) { best1 = d10; bidx1 = k + 0; }
        if (d11 < best1) { best1 = d11; bidx1 = k + 1; }
    }

    // ---- wave-cooperative coalesced epilogue (R3-proven), once per row-set ----
    // LDS gather: lane l reads cbs[idx*64 + l] -> 2-way bank aliasing = free.
    const size_t wave_row0 = (size_t)row0 - lane;
#pragma unroll 4
    for (int l = 0; l < 64; ++l) {
        const int idx = __shfl(bidx0, l, 64);
        out[1 + (wave_row0 + l) * DIM + lane] = cbs[idx * DIM + lane];
    }
    const size_t wave_row1 = (size_t)row1 - lane;
#pragma unroll 4
    for (int l = 0; l < 64; ++l) {
        const int idx = __shfl(bidx1, l, 64);
        out[1 + (wave_row1 + l) * DIM + lane] = cbs[idx * DIM + lane];
    }

    out[1 + (size_t)N_ROWS * DIM + row0] = (float)bidx0;  // coalesced
    out[1 + (size_t)N_ROWS * DIM + row1] = (float)bidx1;

    // loss contribution: sum of both rows' ||x - e||^2 (noise ~1e-5, thr ~2%)
    float lrow = best0 + best1;
#pragma unroll
    for (int off = 32; off > 0; off >>= 1) lrow += __shfl_down(lrow, off, 64);
    if (lane == 0) atomicAdd(loss_acc, lrow);
}

// ---- kernel 3: finalize loss ----
__global__ void fin_kernel(const float* __restrict__ loss_acc,
                           float* __restrict__ out) {
    if (threadIdx.x == 0) {
        float mean_sq = (*loss_acc) / (float)((size_t)N_ROWS * DIM);
        out[0] = 1.25f * mean_sq;  // q_loss + COMMITMENT_COST * e_loss
    }
}

extern "C" void kernel_launch(void* const* d_in, const int* in_sizes, int n_in,
                              void* d_out, int out_size, void* d_ws, size_t ws_size,
                              hipStream_t stream) {
    const float* x  = (const float*)d_in[0];
    const float* cb = (const float*)d_in[1];
    float* out = (float*)d_out;

    float* loss_acc = (float*)d_ws;                 // 4 B accumulator
    float* esq      = (float*)((char*)d_ws + 256);  // 512 floats

    hipMemsetAsync(d_ws, 0, 4, stream);             // zero loss accumulator
    esq_kernel<<<2, 256, 0, stream>>>(cb, esq);
    vq_kernel<<<N_ROWS / (BLK * RPT), BLK, LDS_FLOATS * sizeof(float), stream>>>(
        x, cb, esq, out, loss_acc);
    fin_kernel<<<1, 64, 0, stream>>>(loss_acc, out);
}